// Round 3
// baseline (15486.087 us; speedup 1.0000x reference)
//
#include <hip/hip_runtime.h>

#define NF 481
#define NT 500
#define CH 16
#define HID 32
#define NB 16
#define NSEQ (NB*NF)   // 7696

// conv tiling
#define FT 16          // f outputs per block
#define FH1 28         // staged feat f-halo = FT + 2*(4+2)
#define FH2 20         // y1 f-halo = FT + 2*2
#define TT 16          // t per tile
#define TS 20          // padded t-stride in floats (80 B, 16B-aligned)
#define NTILE 8        // t-tiles per block (one chunk = 128 t)

__device__ __forceinline__ float sig_(float v) { return 1.0f / (1.0f + __expf(-v)); }

#define ACC16(A, W, V0, V1, V2, V3)                                              \
    A[0] = fmaf(W,(V0).x,A[0]);  A[1] = fmaf(W,(V0).y,A[1]);                     \
    A[2] = fmaf(W,(V0).z,A[2]);  A[3] = fmaf(W,(V0).w,A[3]);                     \
    A[4] = fmaf(W,(V1).x,A[4]);  A[5] = fmaf(W,(V1).y,A[5]);                     \
    A[6] = fmaf(W,(V1).z,A[6]);  A[7] = fmaf(W,(V1).w,A[7]);                     \
    A[8] = fmaf(W,(V2).x,A[8]);  A[9] = fmaf(W,(V2).y,A[9]);                     \
    A[10]= fmaf(W,(V2).z,A[10]); A[11]= fmaf(W,(V2).w,A[11]);                    \
    A[12]= fmaf(W,(V3).x,A[12]); A[13]= fmaf(W,(V3).y,A[13]);                    \
    A[14]= fmaf(W,(V3).z,A[14]); A[15]= fmaf(W,(V3).w,A[15])

// -------------------------------------------------------------------------
// Kernel 1: conv1(4->16,k9,p4)+PReLU -> conv2(16->16,k5,p2)+PReLU
// features (B,4,F,T) -> x (N=B*F, T, 16).  Small per-thread acc (<=32 regs)
// to avoid the Round-2 spill (VGPR=256, 10.9 GB scratch traffic).
// -------------------------------------------------------------------------
__global__ __launch_bounds__(256, 3) void conv_kernel(
    const float* __restrict__ feat,
    const float* __restrict__ w1, const float* __restrict__ b1, const float* __restrict__ a1p,
    const float* __restrict__ w2, const float* __restrict__ b2, const float* __restrict__ a2p,
    float* __restrict__ xout)
{
    __shared__ float s_feat[4*FH1*TS];    //  9.0 KB
    __shared__ float s_y1[CH*FH2*TS];     // 25.6 KB
    __shared__ float s_w1[CH*4*9];
    __shared__ float s_w2[CH*CH*5];
    __shared__ float s_b1[CH], s_b2[CH];

    const int b   = blockIdx.x;
    const int f0  = blockIdx.y * FT;
    const int zc  = blockIdx.z;
    const int tid = threadIdx.x;
    const float a1 = a1p[0], a2 = a2p[0];

    for (int i = tid; i < CH*4*9;  i += 256) s_w1[i] = w1[i];
    for (int i = tid; i < CH*CH*5; i += 256) s_w2[i] = w2[i];
    if (tid < CH) { s_b1[tid] = b1[tid]; s_b2[tid] = b2[tid]; }

    for (int it = 0; it < NTILE; it++) {
        const int t0 = zc*(NTILE*TT) + it*TT;
        __syncthreads();   // prev conv2 done reading s_y1 / first-iter weights done

        // ---- stage feature tile: rows (d,ffp), 4 float4 per row ----
        {
            const int q = tid & 3;
            int r = tid >> 2;
            #pragma unroll
            for (int pass = 0; pass < 2; pass++, r += 64) {
                if (r < 4*FH1) {
                    const int d = r / FH1, ffp = r % FH1;
                    const int gf = f0 - 6 + ffp;
                    const int gt = t0 + q*4;
                    float4 v = make_float4(0.f, 0.f, 0.f, 0.f);
                    if (gf >= 0 && gf < NF) {
                        const float* src = feat + ((size_t)(b*4 + d)*NF + gf)*NT + gt;
                        if (gt + 3 < NT) v = *(const float4*)src;
                        else {
                            if (gt + 0 < NT) v.x = src[0];
                            if (gt + 1 < NT) v.y = src[1];
                            if (gt + 2 < NT) v.z = src[2];
                        }
                    }
                    *(float4*)&s_feat[r*TS + q*4] = v;
                }
            }
        }
        __syncthreads();

        // ---- conv1 + PReLU -> s_y1 (zeroed outside valid f = conv2 zero-pad)
        if (tid < 8*FH2) {                     // 160 threads: (cg, fp)
            const int fp = tid % FH2, cg = tid / FH2;
            const int c0 = cg*2, c1 = c0 + 1;
            float A0[TT], A1[TT];
            const float bb0 = s_b1[c0], bb1 = s_b1[c1];
            #pragma unroll
            for (int t = 0; t < TT; t++) { A0[t] = bb0; A1[t] = bb1; }
            #pragma unroll
            for (int d = 0; d < 4; d++) {
                #pragma unroll
                for (int k = 0; k < 9; k++) {
                    const float4* rp = (const float4*)&s_feat[(d*FH1 + fp + k)*TS];
                    const float4 v0 = rp[0], v1 = rp[1], v2 = rp[2], v3 = rp[3];
                    const float w00 = s_w1[(c0*4 + d)*9 + k];
                    const float w10 = s_w1[(c1*4 + d)*9 + k];
                    ACC16(A0, w00, v0, v1, v2, v3);
                    ACC16(A1, w10, v0, v1, v2, v3);
                }
            }
            const int gf1 = f0 - 2 + fp;
            const bool valid = (gf1 >= 0 && gf1 < NF);
            float* d0 = &s_y1[(c0*FH2 + fp)*TS];
            float* d1 = &s_y1[(c1*FH2 + fp)*TS];
            #pragma unroll
            for (int t = 0; t < TT; t++) {
                float u0 = A0[t]; u0 = (u0 >= 0.f) ? u0 : a1*u0;
                float u1 = A1[t]; u1 = (u1 >= 0.f) ? u1 : a1*u1;
                d0[t] = valid ? u0 : 0.f;
                d1[t] = valid ? u1 : 0.f;
            }
        }
        __syncthreads();

        // ---- conv2 + PReLU -> x (N, T, 16) ----
        if (tid < 8*16) {                      // 128 threads: (cg, f)
            const int f = tid % 16, cg = tid / 16;
            const int c0 = cg*2, c1 = c0 + 1;
            float A0[TT], A1[TT];
            const float bb0 = s_b2[c0], bb1 = s_b2[c1];
            #pragma unroll
            for (int t = 0; t < TT; t++) { A0[t] = bb0; A1[t] = bb1; }
            #pragma unroll
            for (int ci = 0; ci < CH; ci++) {
                #pragma unroll
                for (int k = 0; k < 5; k++) {
                    const float4* rp = (const float4*)&s_y1[(ci*FH2 + f + k)*TS];
                    const float4 v0 = rp[0], v1 = rp[1], v2 = rp[2], v3 = rp[3];
                    const float w00 = s_w2[(c0*CH + ci)*5 + k];
                    const float w10 = s_w2[(c1*CH + ci)*5 + k];
                    ACC16(A0, w00, v0, v1, v2, v3);
                    ACC16(A1, w10, v0, v1, v2, v3);
                }
            }
            const int gf = f0 + f;
            if (gf < NF) {
                const size_t n = (size_t)b*NF + gf;
                #pragma unroll
                for (int t = 0; t < TT; t++) {
                    const int gt = t0 + t;
                    if (gt < NT) {
                        float u0 = A0[t]; u0 = (u0 >= 0.f) ? u0 : a2*u0;
                        float u1 = A1[t]; u1 = (u1 >= 0.f) ? u1 : a2*u1;
                        *(float2*)&xout[(n*NT + gt)*CH + c0] = make_float2(u0, u1);
                    }
                }
            }
        }
    }
}

// -------------------------------------------------------------------------
// Kernel 2: GRU + FC + sigmoid.  One wave (64 lanes) per sequence, 4 waves
// per block.  Lane (j, half): owns hidden unit j, computes the `half` part
// of each dot; partials combined with __shfl_xor(.,32).  ~72 weights/lane
// -> ~110 VGPR -> 4 waves/SIMD.  No __syncthreads: waves are independent,
// and intra-wave LDS ops are program-ordered.
// -------------------------------------------------------------------------
#define DOT8(acc, WT, VA, VB)                       \
    acc = fmaf(WT[0], (VA).x, acc);                 \
    acc = fmaf(WT[1], (VA).y, acc);                 \
    acc = fmaf(WT[2], (VA).z, acc);                 \
    acc = fmaf(WT[3], (VA).w, acc);                 \
    acc = fmaf(WT[4], (VB).x, acc);                 \
    acc = fmaf(WT[5], (VB).y, acc);                 \
    acc = fmaf(WT[6], (VB).z, acc);                 \
    acc = fmaf(WT[7], (VB).w, acc)

__global__ __launch_bounds__(256, 4) void gru_kernel(
    const float* __restrict__ xin,   // (NSEQ, NT, 16)
    const float* __restrict__ h0,    // (NSEQ, 32)
    const float* __restrict__ w_ih,  // (96, 16)
    const float* __restrict__ w_hh,  // (96, 32)
    const float* __restrict__ b_ih, const float* __restrict__ b_hh,
    const float* __restrict__ fc_w, const float* __restrict__ fc_b,
    float* __restrict__ prob,        // (NSEQ, NT)
    float* __restrict__ hout)        // (NSEQ, 32)
{
    __shared__ float s_h[4][HID];
    const int wv   = threadIdx.x >> 6;
    const int lane = threadIdx.x & 63;
    const int j    = lane & 31;
    const int half = lane >> 5;
    const size_t n = (size_t)blockIdx.x*4 + wv;   // NSEQ = 7696 = 4*1924

    // per-lane weight slices
    float wir[8], wiz[8], win_[8];
    {
        const float4* p;
        p = (const float4*)(w_ih + (      j)*16 + half*8); *(float4*)&wir[0]  = p[0]; *(float4*)&wir[4]  = p[1];
        p = (const float4*)(w_ih + (32 +  j)*16 + half*8); *(float4*)&wiz[0]  = p[0]; *(float4*)&wiz[4]  = p[1];
        p = (const float4*)(w_ih + (64 +  j)*16 + half*8); *(float4*)&win_[0] = p[0]; *(float4*)&win_[4] = p[1];
    }
    float whr[16], whz[16], whn[16];
    {
        const float4* p;
        p = (const float4*)(w_hh + (      j)*32 + half*16);
        *(float4*)&whr[0] = p[0]; *(float4*)&whr[4] = p[1]; *(float4*)&whr[8] = p[2]; *(float4*)&whr[12] = p[3];
        p = (const float4*)(w_hh + (32 +  j)*32 + half*16);
        *(float4*)&whz[0] = p[0]; *(float4*)&whz[4] = p[1]; *(float4*)&whz[8] = p[2]; *(float4*)&whz[12] = p[3];
        p = (const float4*)(w_hh + (64 +  j)*32 + half*16);
        *(float4*)&whn[0] = p[0]; *(float4*)&whn[4] = p[1]; *(float4*)&whn[8] = p[2]; *(float4*)&whn[12] = p[3];
    }
    const float brr = b_ih[j]      + b_hh[j];
    const float bzz = b_ih[32 + j] + b_hh[32 + j];
    const float bin_ = b_ih[64 + j];
    const float bhn  = b_hh[64 + j];
    const float fw = fc_w[j];
    const float fb = fc_b[0];

    float h = h0[n*HID + j];
    if (half == 0) s_h[wv][j] = h;
    __builtin_amdgcn_wave_barrier();

    const float* xb = xin + (size_t)n*NT*CH + half*8;
    float4 cx0 = *(const float4*)(xb);
    float4 cx1 = *(const float4*)(xb + 4);

    for (int t = 0; t < NT; t++) {
        const int tn = (t + 1 < NT) ? t + 1 : NT - 1;
        const float4 nx0 = *(const float4*)(xb + tn*16);
        const float4 nx1 = *(const float4*)(xb + tn*16 + 4);

        // x partials (length-8 dots)
        float xr = 0.f, xz = 0.f, xnp = 0.f;
        DOT8(xr,  wir,  cx0, cx1);
        DOT8(xz,  wiz,  cx0, cx1);
        DOT8(xnp, win_, cx0, cx1);

        // h partials (length-16 dots, broadcast LDS reads)
        const float4* hp = (const float4*)&s_h[wv][half*16];
        const float4 h0v = hp[0], h1v = hp[1], h2v = hp[2], h3v = hp[3];
        float hr = 0.f, hz = 0.f, hnp = 0.f;
        DOT8(hr,  (&whr[0]), h0v, h1v);  DOT8(hr,  (&whr[8]), h2v, h3v);
        DOT8(hz,  (&whz[0]), h0v, h1v);  DOT8(hz,  (&whz[8]), h2v, h3v);
        DOT8(hnp, (&whn[0]), h0v, h1v);  DOT8(hnp, (&whn[8]), h2v, h3v);

        // combine halves
        float prz = xr + hr;  prz += __shfl_xor(prz, 32);
        float pzz = xz + hz;  pzz += __shfl_xor(pzz, 32);
        float xn = xnp + __shfl_xor(xnp, 32) + bin_;
        float hn = hnp + __shfl_xor(hnp, 32) + bhn;

        const float r = sig_(prz + brr);
        const float z = sig_(pzz + bzz);
        const float aa = xn + r*hn;
        const float nn = 2.f*sig_(2.f*aa) - 1.f;       // tanh
        const float hnew = (1.f - z)*nn + z*h;

        // FC + sigmoid (butterfly within 32-lane half)
        float pa = fw * hnew;
        pa += __shfl_xor(pa, 1);
        pa += __shfl_xor(pa, 2);
        pa += __shfl_xor(pa, 4);
        pa += __shfl_xor(pa, 8);
        pa += __shfl_xor(pa, 16);
        if (lane == 0) prob[n*(size_t)NT + t] = sig_(pa + fb);

        if (half == 0) s_h[wv][j] = hnew;
        __builtin_amdgcn_wave_barrier();
        h = hnew;
        cx0 = nx0; cx1 = nx1;
    }

    if (half == 0) hout[n*HID + j] = h;
}

// -------------------------------------------------------------------------
extern "C" void kernel_launch(void* const* d_in, const int* in_sizes, int n_in,
                              void* d_out, int out_size, void* d_ws, size_t ws_size,
                              hipStream_t stream)
{
    const float* feat = (const float*)d_in[0];
    const float* h0   = (const float*)d_in[1];
    const float* w1   = (const float*)d_in[2];
    const float* b1   = (const float*)d_in[3];
    const float* a1   = (const float*)d_in[4];
    const float* w2   = (const float*)d_in[5];
    const float* b2   = (const float*)d_in[6];
    const float* a2   = (const float*)d_in[7];
    const float* wih  = (const float*)d_in[8];
    const float* whh  = (const float*)d_in[9];
    const float* bih  = (const float*)d_in[10];
    const float* bhh  = (const float*)d_in[11];
    const float* fcw  = (const float*)d_in[12];
    const float* fcb  = (const float*)d_in[13];

    float* xbuf = (float*)d_ws;                    // NSEQ*NT*16 floats = 246.3 MB
    float* prob = (float*)d_out;                   // (B, F, T)
    float* hout = prob + (size_t)NSEQ*NT;          // (1, NSEQ, 32)

    dim3 cgrid(NB, (NF + FT - 1)/FT, 4);           // (16, 31, 4): 128 t per chunk
    conv_kernel<<<cgrid, 256, 0, stream>>>(feat, w1, b1, a1, w2, b2, a2, xbuf);
    gru_kernel<<<NSEQ/4, 256, 0, stream>>>(xbuf, h0, wih, whh, bih, bhh, fcw, fcb, prob, hout);
}